// Round 1
// baseline (454.690 us; speedup 1.0000x reference)
//
#include <hip/hip_runtime.h>
#include <math.h>

// DP-GCN constants (EPS=1, ALPHA=0.5, DELTA=1):
//   transformed = ((e+1)*x - 1) * (1/(e-1)) + 0.5 = C1*x + C0
#define C1 2.163953413738653f
#define C0 -0.081976706869326f

__global__ void k_zero_i32(int* __restrict__ p, int n) {
    int i = blockIdx.x * blockDim.x + threadIdx.x;
    if (i < n) p[i] = 0;
}

// deg[i] = #edges with row==i  (self loop +1 added in k_dis)
__global__ void k_deg(const int* __restrict__ row, int E, int* __restrict__ deg) {
    int e = blockIdx.x * blockDim.x + threadIdx.x;
    if (e < E) atomicAdd(&deg[row[e]], 1);
}

__global__ void k_dis(const int* __restrict__ deg, float* __restrict__ dis, int n) {
    int i = blockIdx.x * blockDim.x + threadIdx.x;
    if (i < n) dis[i] = rsqrtf((float)(deg[i] + 1));
}

// agg1 initialized with the self-loop message: dis[i]^2 * (p ? C1*x+C0 : x)
__global__ void k_self1(const float* __restrict__ x, const int* __restrict__ priv,
                        const float* __restrict__ dis, float* __restrict__ agg1, int n) {
    int idx = blockIdx.x * blockDim.x + threadIdx.x;
    if (idx < n * 64) {
        int nn = idx >> 6;
        float dv = dis[nn];
        float xv = x[idx];
        float t = priv[nn] ? fmaf(C1, xv, C0) : xv;
        agg1[idx] = dv * dv * t;
    }
}

// one 64-lane wave per edge; lane = feature dim (coalesced gather + atomic)
__global__ void k_scatter1(const float* __restrict__ x, const int* __restrict__ row,
                           const int* __restrict__ col, const int* __restrict__ priv,
                           const float* __restrict__ dis, float* __restrict__ agg1, int E) {
    int t = blockIdx.x * blockDim.x + threadIdx.x;
    int e = t >> 6, d = t & 63;
    if (e < E) {
        int r = row[e], c = col[e];
        float w = dis[r] * dis[c];
        float xv = x[(size_t)r * 64 + d];
        float m = priv[r] ? fmaf(C1, xv, C0) : xv;
        atomicAdd(&agg1[(size_t)c * 64 + d], w * m);
    }
}

// fused MLP: hp[n] = relu(agg1[n] @ W1 + b1) @ W2   (W1,W2,b1 in LDS)
__global__ __launch_bounds__(256) void k_mlp(const float* __restrict__ agg1,
                                             const float* __restrict__ W1,
                                             const float* __restrict__ b1,
                                             const float* __restrict__ W2,
                                             float* __restrict__ hp, int N) {
    __shared__ float W1s[64 * 128];   // 32 KB
    __shared__ float W2s[128 * 32];   // 16 KB
    __shared__ float b1s[128];
    __shared__ float xs[2][64];
    __shared__ float hid[2][128];
    __shared__ float red[2][128];

    for (int i = threadIdx.x; i < 64 * 128; i += 256) W1s[i] = W1[i];
    for (int i = threadIdx.x; i < 128 * 32; i += 256) W2s[i] = W2[i];
    if (threadIdx.x < 128) b1s[threadIdx.x] = b1[threadIdx.x];
    __syncthreads();

    int sub = threadIdx.x >> 7;   // which of 2 concurrent nodes
    int k   = threadIdx.x & 127;  // hidden index
    int j   = k & 31, q = k >> 5;

    for (int base = blockIdx.x * 2; base < N; base += gridDim.x * 2) {
        int n = base + sub;
        if (threadIdx.x < 128) {
            int nn = base + (threadIdx.x >> 6);
            int d = threadIdx.x & 63;
            xs[threadIdx.x >> 6][d] = (nn < N) ? agg1[(size_t)nn * 64 + d] : 0.f;
        }
        __syncthreads();

        float acc = b1s[k];
        #pragma unroll
        for (int d = 0; d < 64; ++d) acc = fmaf(xs[sub][d], W1s[d * 128 + k], acc);
        hid[sub][k] = fmaxf(acc, 0.f);
        __syncthreads();

        float p2 = 0.f;
        #pragma unroll
        for (int kk = 0; kk < 32; ++kk)
            p2 = fmaf(hid[sub][q * 32 + kk], W2s[(q * 32 + kk) * 32 + j], p2);
        red[sub][k] = p2;
        __syncthreads();

        if (q == 0 && n < N)
            hp[(size_t)n * 32 + j] = red[sub][j] + red[sub][32 + j] + red[sub][64 + j] + red[sub][96 + j];
        __syncthreads();
    }
}

// out initialized with bias + conv2 self-loop: b2[j] - dis^2 * hp[n][j]
__global__ void k_out_init(const float* __restrict__ hp, const float* __restrict__ dis,
                           const float* __restrict__ b2, float* __restrict__ out, int n) {
    int idx = blockIdx.x * blockDim.x + threadIdx.x;
    if (idx < n * 32) {
        int nn = idx >> 5, jj = idx & 31;
        float dv = dis[nn];
        out[idx] = b2[jj] - dv * dv * hp[idx];
    }
}

// 32 lanes per edge (2 edges per wave)
__global__ void k_scatter2(const float* __restrict__ hp, const int* __restrict__ row,
                           const int* __restrict__ col, const float* __restrict__ dis,
                           float* __restrict__ out, int E) {
    int t = blockIdx.x * blockDim.x + threadIdx.x;
    int e = t >> 5, jj = t & 31;
    if (e < E) {
        int r = row[e], c = col[e];
        float w = dis[r] * dis[c];
        atomicAdd(&out[(size_t)c * 32 + jj], -w * hp[(size_t)r * 32 + jj]);
    }
}

extern "C" void kernel_launch(void* const* d_in, const int* in_sizes, int n_in,
                              void* d_out, int out_size, void* d_ws, size_t ws_size,
                              hipStream_t stream) {
    const float* x    = (const float*)d_in[0];
    const int*   ei   = (const int*)d_in[1];
    const int*   priv = (const int*)d_in[2];
    const float* W1   = (const float*)d_in[3];
    const float* b1   = (const float*)d_in[4];
    const float* W2   = (const float*)d_in[5];
    const float* b2   = (const float*)d_in[6];
    float* out = (float*)d_out;

    const int N = in_sizes[2];
    const int E = in_sizes[1] / 2;
    const int* row = ei;
    const int* col = ei + E;

    // workspace layout (256B-aligned regions)
    char* ws = (char*)d_ws;
    size_t off = 0;
    auto take = [&](size_t bytes) { char* p = ws + off; off = (off + bytes + 255) & ~(size_t)255; return p; };
    int*   deg  = (int*)  take((size_t)N * 4);
    float* dis  = (float*)take((size_t)N * 4);
    float* agg1 = (float*)take((size_t)N * 64 * 4);
    float* hp   = (float*)take((size_t)N * 32 * 4);
    (void)ws_size;

    k_zero_i32<<<(N + 255) / 256, 256, 0, stream>>>(deg, N);
    k_deg<<<(E + 255) / 256, 256, 0, stream>>>(row, E, deg);
    k_dis<<<(N + 255) / 256, 256, 0, stream>>>(deg, dis, N);
    k_self1<<<((size_t)N * 64 + 255) / 256, 256, 0, stream>>>(x, priv, dis, agg1, N);
    k_scatter1<<<((size_t)E * 64 + 255) / 256, 256, 0, stream>>>(x, row, col, priv, dis, agg1, E);
    k_mlp<<<2048, 256, 0, stream>>>(agg1, W1, b1, W2, hp, N);
    k_out_init<<<((size_t)N * 32 + 255) / 256, 256, 0, stream>>>(hp, dis, b2, out, N);
    k_scatter2<<<((size_t)E * 32 + 255) / 256, 256, 0, stream>>>(hp, row, col, dis, out, E);
}

// Round 2
// 350.027 us; speedup vs baseline: 1.2990x; 1.2990x over previous
//
#include <hip/hip_runtime.h>
#include <math.h>

// DP-GCN constants (EPS=1, ALPHA=0.5, DELTA=1):
//   transformed = ((e+1)*x - 1) * (1/(e-1)) + 0.5 = C1*x + C0
#define C1 2.163953413738653f
#define C0 -0.081976706869326f

__global__ void k_zero3(int* __restrict__ a, int* __restrict__ b, int* __restrict__ c, int n) {
    int i = blockIdx.x * blockDim.x + threadIdx.x;
    if (i < n) { a[i] = 0; b[i] = 0; c[i] = 0; }
}

// degR[i] = out-degree by row (for norm); cntC[i] = in-degree by col (for CSR)
__global__ void k_count(const int* __restrict__ row, const int* __restrict__ col, int E,
                        int* __restrict__ degR, int* __restrict__ cntC) {
    int e = blockIdx.x * blockDim.x + threadIdx.x;
    if (e < E) {
        atomicAdd(&degR[row[e]], 1);
        atomicAdd(&cntC[col[e]], 1);
    }
}

__global__ void k_dis(const int* __restrict__ degR, float* __restrict__ dis, int n) {
    int i = blockIdx.x * blockDim.x + threadIdx.x;
    if (i < n) dis[i] = rsqrtf((float)(degR[i] + 1));   // +1 self loop
}

// ---- 2-level exclusive scan of cntC -> colStart ----
__global__ void k_scan_a(const int* __restrict__ cnt, int* __restrict__ excl,
                         int* __restrict__ bsum, int n) {
    __shared__ int s[256];
    int idx = blockIdx.x * 256 + threadIdx.x;
    int v = (idx < n) ? cnt[idx] : 0;
    s[threadIdx.x] = v;
    __syncthreads();
    for (int off = 1; off < 256; off <<= 1) {
        int t = (threadIdx.x >= off) ? s[threadIdx.x - off] : 0;
        __syncthreads();
        s[threadIdx.x] += t;
        __syncthreads();
    }
    if (idx < n) excl[idx] = s[threadIdx.x] - v;
    if (threadIdx.x == 255) bsum[blockIdx.x] = s[255];
}

__global__ void k_scan_b(const int* __restrict__ bsum, int* __restrict__ boff, int nb) {
    __shared__ int s[256];
    int v = (threadIdx.x < nb) ? bsum[threadIdx.x] : 0;
    s[threadIdx.x] = v;
    __syncthreads();
    for (int off = 1; off < 256; off <<= 1) {
        int t = (threadIdx.x >= off) ? s[threadIdx.x - off] : 0;
        __syncthreads();
        s[threadIdx.x] += t;
        __syncthreads();
    }
    if (threadIdx.x < nb) boff[threadIdx.x] = s[threadIdx.x] - v;
}

__global__ void k_scan_c(int* __restrict__ excl, const int* __restrict__ boff, int n) {
    int idx = blockIdx.x * 256 + threadIdx.x;
    if (idx < n) excl[idx] += boff[blockIdx.x];
}

// counting-sort fill: eSrc[pos] = row, bucketed by col
__global__ void k_fill(const int* __restrict__ row, const int* __restrict__ col, int E,
                       const int* __restrict__ colStart, int* __restrict__ fillCnt,
                       int* __restrict__ eSrc) {
    int e = blockIdx.x * blockDim.x + threadIdx.x;
    if (e < E) {
        int c = col[e];
        int pos = colStart[c] + atomicAdd(&fillCnt[c], 1);
        eSrc[pos] = row[e];
    }
}

// conv1 aggregation by gather: one 64-lane wave per destination node
__global__ __launch_bounds__(256) void k_gather1(const float* __restrict__ x,
                                                 const int* __restrict__ eSrc,
                                                 const int* __restrict__ colStart,
                                                 const int* __restrict__ cntC,
                                                 const int* __restrict__ priv,
                                                 const float* __restrict__ dis,
                                                 float* __restrict__ agg1, int N) {
    int t = blockIdx.x * blockDim.x + threadIdx.x;
    int c = t >> 6, d = t & 63;
    if (c >= N) return;
    float dc = dis[c];
    // self loop term
    float xv = x[(size_t)c * 64 + d];
    float tv = priv[c] ? fmaf(C1, xv, C0) : xv;
    float s = dc * tv;
    int start = colStart[c], cnt = cntC[c];
    for (int base = 0; base < cnt; base += 64) {
        int m = min(cnt - base, 64);
        int   r_l  = (d < m) ? eSrc[start + base + d] : 0;
        float dr_l = (d < m) ? dis[r_l] : 0.f;
        int   pv_l = (d < m) ? priv[r_l] : 0;
        for (int k = 0; k < m; ++k) {
            int   r  = __shfl(r_l, k);
            float dr = __shfl(dr_l, k);
            int   pv = __shfl(pv_l, k);
            float xr = x[(size_t)r * 64 + d];
            float tr = pv ? fmaf(C1, xr, C0) : xr;
            s = fmaf(dr, tr, s);
        }
    }
    agg1[(size_t)c * 64 + d] = dc * s;
}

// fused MLP: hp[n] = relu(agg1[n] @ W1 + b1) @ W2   (W1,W2,b1 in LDS)
__global__ __launch_bounds__(256) void k_mlp(const float* __restrict__ agg1,
                                             const float* __restrict__ W1,
                                             const float* __restrict__ b1,
                                             const float* __restrict__ W2,
                                             float* __restrict__ hp, int N) {
    __shared__ float W1s[64 * 128];   // 32 KB
    __shared__ float W2s[128 * 32];   // 16 KB
    __shared__ float b1s[128];
    __shared__ float xs[2][64];
    __shared__ float hid[2][128];
    __shared__ float red[2][128];

    for (int i = threadIdx.x; i < 64 * 128; i += 256) W1s[i] = W1[i];
    for (int i = threadIdx.x; i < 128 * 32; i += 256) W2s[i] = W2[i];
    if (threadIdx.x < 128) b1s[threadIdx.x] = b1[threadIdx.x];
    __syncthreads();

    int sub = threadIdx.x >> 7;   // which of 2 concurrent nodes
    int k   = threadIdx.x & 127;  // hidden index
    int j   = k & 31, q = k >> 5;

    for (int base = blockIdx.x * 2; base < N; base += gridDim.x * 2) {
        int n = base + sub;
        if (threadIdx.x < 128) {
            int nn = base + (threadIdx.x >> 6);
            int d = threadIdx.x & 63;
            xs[threadIdx.x >> 6][d] = (nn < N) ? agg1[(size_t)nn * 64 + d] : 0.f;
        }
        __syncthreads();

        float acc = b1s[k];
        #pragma unroll
        for (int d = 0; d < 64; ++d) acc = fmaf(xs[sub][d], W1s[d * 128 + k], acc);
        hid[sub][k] = fmaxf(acc, 0.f);
        __syncthreads();

        float p2 = 0.f;
        #pragma unroll
        for (int kk = 0; kk < 32; ++kk)
            p2 = fmaf(hid[sub][q * 32 + kk], W2s[(q * 32 + kk) * 32 + j], p2);
        red[sub][k] = p2;
        __syncthreads();

        if (q == 0 && n < N)
            hp[(size_t)n * 32 + j] = red[sub][j] + red[sub][32 + j] + red[sub][64 + j] + red[sub][96 + j];
        __syncthreads();
    }
}

// conv2 aggregation by gather: 32 lanes per destination node (shfl width 32)
__global__ __launch_bounds__(256) void k_gather2(const float* __restrict__ hp,
                                                 const int* __restrict__ eSrc,
                                                 const int* __restrict__ colStart,
                                                 const int* __restrict__ cntC,
                                                 const float* __restrict__ dis,
                                                 const float* __restrict__ b2,
                                                 float* __restrict__ out, int N) {
    int t = blockIdx.x * blockDim.x + threadIdx.x;
    int c = t >> 5, j = t & 31;
    if (c >= N) return;
    float dc = dis[c];
    float s = dc * hp[(size_t)c * 32 + j];   // self loop
    int start = colStart[c], cnt = cntC[c];
    for (int base = 0; base < cnt; base += 32) {
        int m = min(cnt - base, 32);
        int   r_l  = (j < m) ? eSrc[start + base + j] : 0;
        float dr_l = (j < m) ? dis[r_l] : 0.f;
        for (int k = 0; k < m; ++k) {
            int   r  = __shfl(r_l, k, 32);
            float dr = __shfl(dr_l, k, 32);
            s = fmaf(dr, hp[(size_t)r * 32 + j], s);
        }
    }
    out[(size_t)c * 32 + j] = b2[j] - dc * s;   // msg2 = -norm*h[row]
}

extern "C" void kernel_launch(void* const* d_in, const int* in_sizes, int n_in,
                              void* d_out, int out_size, void* d_ws, size_t ws_size,
                              hipStream_t stream) {
    const float* x    = (const float*)d_in[0];
    const int*   ei   = (const int*)d_in[1];
    const int*   priv = (const int*)d_in[2];
    const float* W1   = (const float*)d_in[3];
    const float* b1   = (const float*)d_in[4];
    const float* W2   = (const float*)d_in[5];
    const float* b2   = (const float*)d_in[6];
    float* out = (float*)d_out;

    const int N = in_sizes[2];
    const int E = in_sizes[1] / 2;
    const int* row = ei;
    const int* col = ei + E;

    char* ws = (char*)d_ws;
    size_t off = 0;
    auto take = [&](size_t bytes) { char* p = ws + off; off = (off + bytes + 255) & ~(size_t)255; return p; };
    int*   degR     = (int*)  take((size_t)N * 4);
    int*   cntC     = (int*)  take((size_t)N * 4);
    int*   fillCnt  = (int*)  take((size_t)N * 4);
    int*   colStart = (int*)  take((size_t)N * 4);
    float* dis      = (float*)take((size_t)N * 4);
    int*   bsum     = (int*)  take(256 * 4);
    int*   boff     = (int*)  take(256 * 4);
    int*   eSrc     = (int*)  take((size_t)E * 4);
    float* agg1     = (float*)take((size_t)N * 64 * 4);
    float* hp       = (float*)take((size_t)N * 32 * 4);
    (void)ws_size;

    const int nb = (N + 255) / 256;   // scan blocks (196 <= 256)

    k_zero3 <<<nb, 256, 0, stream>>>(degR, cntC, fillCnt, N);
    k_count <<<(E + 255) / 256, 256, 0, stream>>>(row, col, E, degR, cntC);
    k_dis   <<<nb, 256, 0, stream>>>(degR, dis, N);
    k_scan_a<<<nb, 256, 0, stream>>>(cntC, colStart, bsum, N);
    k_scan_b<<<1, 256, 0, stream>>>(bsum, boff, nb);
    k_scan_c<<<nb, 256, 0, stream>>>(colStart, boff, N);
    k_fill  <<<(E + 255) / 256, 256, 0, stream>>>(row, col, E, colStart, fillCnt, eSrc);
    k_gather1<<<((size_t)N * 64 + 255) / 256, 256, 0, stream>>>(x, eSrc, colStart, cntC, priv, dis, agg1, N);
    k_mlp   <<<2048, 256, 0, stream>>>(agg1, W1, b1, W2, hp, N);
    k_gather2<<<((size_t)N * 32 + 255) / 256, 256, 0, stream>>>(hp, eSrc, colStart, cntC, dis, b2, out, N);
}

// Round 3
// 304.406 us; speedup vs baseline: 1.4937x; 1.1499x over previous
//
#include <hip/hip_runtime.h>
#include <math.h>

// DP-GCN constants (EPS=1, ALPHA=0.5, DELTA=1):
//   transformed = ((e+1)*x - 1) * (1/(e-1)) + 0.5 = C1*x + C0
#define C1 2.163953413738653f
#define C0 -0.081976706869326f

__global__ void k_zero3(int* __restrict__ a, int* __restrict__ b, int* __restrict__ c, int n) {
    int i = blockIdx.x * blockDim.x + threadIdx.x;
    if (i < n) { a[i] = 0; b[i] = 0; c[i] = 0; }
}

__global__ void k_count(const int* __restrict__ row, const int* __restrict__ col, int E,
                        int* __restrict__ degR, int* __restrict__ cntC) {
    int e = blockIdx.x * blockDim.x + threadIdx.x;
    if (e < E) {
        atomicAdd(&degR[row[e]], 1);
        atomicAdd(&cntC[col[e]], 1);
    }
}

__global__ void k_dis(const int* __restrict__ degR, float* __restrict__ dis, int n) {
    int i = blockIdx.x * blockDim.x + threadIdx.x;
    if (i < n) dis[i] = rsqrtf((float)(degR[i] + 1));   // +1 self loop
}

// ---- 2-level exclusive scan of cntC -> colStart ----
__global__ void k_scan_a(const int* __restrict__ cnt, int* __restrict__ excl,
                         int* __restrict__ bsum, int n) {
    __shared__ int s[256];
    int idx = blockIdx.x * 256 + threadIdx.x;
    int v = (idx < n) ? cnt[idx] : 0;
    s[threadIdx.x] = v;
    __syncthreads();
    for (int off = 1; off < 256; off <<= 1) {
        int t = (threadIdx.x >= off) ? s[threadIdx.x - off] : 0;
        __syncthreads();
        s[threadIdx.x] += t;
        __syncthreads();
    }
    if (idx < n) excl[idx] = s[threadIdx.x] - v;
    if (threadIdx.x == 255) bsum[blockIdx.x] = s[255];
}

__global__ void k_scan_b(const int* __restrict__ bsum, int* __restrict__ boff, int nb) {
    __shared__ int s[256];
    int v = (threadIdx.x < nb) ? bsum[threadIdx.x] : 0;
    s[threadIdx.x] = v;
    __syncthreads();
    for (int off = 1; off < 256; off <<= 1) {
        int t = (threadIdx.x >= off) ? s[threadIdx.x - off] : 0;
        __syncthreads();
        s[threadIdx.x] += t;
        __syncthreads();
    }
    if (threadIdx.x < nb) boff[threadIdx.x] = s[threadIdx.x] - v;
}

__global__ void k_scan_c(int* __restrict__ excl, const int* __restrict__ boff, int n) {
    int idx = blockIdx.x * 256 + threadIdx.x;
    if (idx < n) excl[idx] += boff[blockIdx.x];
}

__global__ void k_fill(const int* __restrict__ row, const int* __restrict__ col, int E,
                       const int* __restrict__ colStart, int* __restrict__ fillCnt,
                       int* __restrict__ eSrc) {
    int e = blockIdx.x * blockDim.x + threadIdx.x;
    if (e < E) {
        int c = col[e];
        int pos = colStart[c] + atomicAdd(&fillCnt[c], 1);
        eSrc[pos] = row[e];
    }
}

// conv1 aggregation by gather: one 64-lane wave per destination node
__global__ __launch_bounds__(256) void k_gather1(const float* __restrict__ x,
                                                 const int* __restrict__ eSrc,
                                                 const int* __restrict__ colStart,
                                                 const int* __restrict__ cntC,
                                                 const int* __restrict__ priv,
                                                 const float* __restrict__ dis,
                                                 float* __restrict__ agg1, int N) {
    int t = blockIdx.x * blockDim.x + threadIdx.x;
    int c = t >> 6, d = t & 63;
    if (c >= N) return;
    float dc = dis[c];
    float xv = x[(size_t)c * 64 + d];
    float tv = priv[c] ? fmaf(C1, xv, C0) : xv;
    float s = dc * tv;
    int start = colStart[c], cnt = cntC[c];
    for (int base = 0; base < cnt; base += 64) {
        int m = min(cnt - base, 64);
        int   r_l  = (d < m) ? eSrc[start + base + d] : 0;
        float dr_l = (d < m) ? dis[r_l] : 0.f;
        int   pv_l = (d < m) ? priv[r_l] : 0;
        for (int k = 0; k < m; ++k) {
            int   r  = __shfl(r_l, k);
            float dr = __shfl(dr_l, k);
            int   pv = __shfl(pv_l, k);
            float xr = x[(size_t)r * 64 + d];
            float tr = pv ? fmaf(C1, xr, C0) : xr;
            s = fmaf(dr, tr, s);
        }
    }
    agg1[(size_t)c * 64 + d] = dc * s;
}

// fused MLP: hp = relu(agg1 @ W1 + b1) @ W2, one 64-node tile per block.
// LDS: hidT[128][68] (rows 0..63 double as transposed A-tile), W2s[128][32].
__global__ __launch_bounds__(256) void k_mlp_fused(const float* __restrict__ agg1,
                                                   const float* __restrict__ W1,
                                                   const float* __restrict__ b1,
                                                   const float* __restrict__ W2,
                                                   float* __restrict__ hp, int N) {
    __shared__ float hidT[128 * 68];        // 34816 B; As = rows 0..63
    __shared__ float W2s[128 * 32];         // 16 KB
    float* As = hidT;
    const int t = threadIdx.x;
    const int base = blockIdx.x * 64;

    // stage W2 (float4)
    for (int i = t * 4; i < 128 * 32; i += 1024)
        *(float4*)&W2s[i] = *(const float4*)&W2[i];

    // stage A-tile transposed: As[k][m] = agg1[base+m][k]
    {
        int kq = t & 15, mm = t >> 4;       // kq: k-quad, mm: 0..15
        #pragma unroll
        for (int p = 0; p < 4; ++p) {
            int m = mm + p * 16;
            int node = base + m;
            if (node >= N) node = N - 1;    // clamp (results unused for OOB rows)
            const float4 v = *(const float4*)&agg1[(size_t)node * 64 + kq * 4];
            As[(kq * 4 + 0) * 68 + m] = v.x;
            As[(kq * 4 + 1) * 68 + m] = v.y;
            As[(kq * 4 + 2) * 68 + m] = v.z;
            As[(kq * 4 + 3) * 68 + m] = v.w;
        }
    }
    __syncthreads();

    // ---- layer 1: out tile 64m x 128n, thread = 8m x 4n ----
    const int tn = t & 31;                  // n-quad: cols tn*4..+3
    const int tm = t >> 5;                  // m-octet: rows tm*8..+7
    float4 bv = *(const float4*)&b1[tn * 4];
    float acc[8][4];
    #pragma unroll
    for (int i = 0; i < 8; ++i) {
        acc[i][0] = bv.x; acc[i][1] = bv.y; acc[i][2] = bv.z; acc[i][3] = bv.w;
    }
    #pragma unroll 4
    for (int k = 0; k < 64; ++k) {
        float4 w  = *(const float4*)&W1[k * 128 + tn * 4];   // L1-resident
        float4 a0 = *(const float4*)&As[k * 68 + tm * 8];
        float4 a1 = *(const float4*)&As[k * 68 + tm * 8 + 4];
        const float av[8] = {a0.x, a0.y, a0.z, a0.w, a1.x, a1.y, a1.z, a1.w};
        #pragma unroll
        for (int i = 0; i < 8; ++i) {
            acc[i][0] = fmaf(av[i], w.x, acc[i][0]);
            acc[i][1] = fmaf(av[i], w.y, acc[i][1]);
            acc[i][2] = fmaf(av[i], w.z, acc[i][2]);
            acc[i][3] = fmaf(av[i], w.w, acc[i][3]);
        }
    }
    __syncthreads();   // all As reads done before hidT overwrites it

    // write hid tile transposed: hidT[kh][m], kh = tn*4+j, m = tm*8+i, relu
    #pragma unroll
    for (int j = 0; j < 4; ++j)
        #pragma unroll
        for (int i = 0; i < 8; ++i)
            hidT[(tn * 4 + j) * 68 + tm * 8 + i] = fmaxf(acc[i][j], 0.f);
    __syncthreads();

    // ---- layer 2: out tile 64m x 32o, thread = 4m x 2o ----
    const int to  = t & 15;                 // o-pair: cols to*2..+1
    const int tm2 = t >> 4;                 // m-quad: rows tm2*4..+3
    float o0[4] = {0.f, 0.f, 0.f, 0.f};
    float o1[4] = {0.f, 0.f, 0.f, 0.f};
    #pragma unroll 4
    for (int kh = 0; kh < 128; ++kh) {
        float4 a = *(const float4*)&hidT[kh * 68 + tm2 * 4];
        float2 w = *(const float2*)&W2s[kh * 32 + to * 2];
        const float av[4] = {a.x, a.y, a.z, a.w};
        #pragma unroll
        for (int i = 0; i < 4; ++i) {
            o0[i] = fmaf(av[i], w.x, o0[i]);
            o1[i] = fmaf(av[i], w.y, o1[i]);
        }
    }
    #pragma unroll
    for (int i = 0; i < 4; ++i) {
        int node = base + tm2 * 4 + i;
        if (node < N)
            *(float2*)&hp[(size_t)node * 32 + to * 2] = make_float2(o0[i], o1[i]);
    }
}

// conv2 aggregation by gather: 32 lanes per destination node
__global__ __launch_bounds__(256) void k_gather2(const float* __restrict__ hp,
                                                 const int* __restrict__ eSrc,
                                                 const int* __restrict__ colStart,
                                                 const int* __restrict__ cntC,
                                                 const float* __restrict__ dis,
                                                 const float* __restrict__ b2,
                                                 float* __restrict__ out, int N) {
    int t = blockIdx.x * blockDim.x + threadIdx.x;
    int c = t >> 5, j = t & 31;
    if (c >= N) return;
    float dc = dis[c];
    float s = dc * hp[(size_t)c * 32 + j];   // self loop
    int start = colStart[c], cnt = cntC[c];
    for (int base = 0; base < cnt; base += 32) {
        int m = min(cnt - base, 32);
        int   r_l  = (j < m) ? eSrc[start + base + j] : 0;
        float dr_l = (j < m) ? dis[r_l] : 0.f;
        for (int k = 0; k < m; ++k) {
            int   r  = __shfl(r_l, k, 32);
            float dr = __shfl(dr_l, k, 32);
            s = fmaf(dr, hp[(size_t)r * 32 + j], s);
        }
    }
    out[(size_t)c * 32 + j] = b2[j] - dc * s;   // msg2 = -norm*h[row]
}

extern "C" void kernel_launch(void* const* d_in, const int* in_sizes, int n_in,
                              void* d_out, int out_size, void* d_ws, size_t ws_size,
                              hipStream_t stream) {
    const float* x    = (const float*)d_in[0];
    const int*   ei   = (const int*)d_in[1];
    const int*   priv = (const int*)d_in[2];
    const float* W1   = (const float*)d_in[3];
    const float* b1   = (const float*)d_in[4];
    const float* W2   = (const float*)d_in[5];
    const float* b2   = (const float*)d_in[6];
    float* out = (float*)d_out;

    const int N = in_sizes[2];
    const int E = in_sizes[1] / 2;
    const int* row = ei;
    const int* col = ei + E;

    char* ws = (char*)d_ws;
    size_t off = 0;
    auto take = [&](size_t bytes) { char* p = ws + off; off = (off + bytes + 255) & ~(size_t)255; return p; };
    int*   degR     = (int*)  take((size_t)N * 4);
    int*   cntC     = (int*)  take((size_t)N * 4);
    int*   fillCnt  = (int*)  take((size_t)N * 4);
    int*   colStart = (int*)  take((size_t)N * 4);
    float* dis      = (float*)take((size_t)N * 4);
    int*   bsum     = (int*)  take(256 * 4);
    int*   boff     = (int*)  take(256 * 4);
    int*   eSrc     = (int*)  take((size_t)E * 4);
    float* agg1     = (float*)take((size_t)N * 64 * 4);
    float* hp       = (float*)take((size_t)N * 32 * 4);
    (void)ws_size;

    const int nb = (N + 255) / 256;

    k_zero3 <<<nb, 256, 0, stream>>>(degR, cntC, fillCnt, N);
    k_count <<<(E + 255) / 256, 256, 0, stream>>>(row, col, E, degR, cntC);
    k_dis   <<<nb, 256, 0, stream>>>(degR, dis, N);
    k_scan_a<<<nb, 256, 0, stream>>>(cntC, colStart, bsum, N);
    k_scan_b<<<1, 256, 0, stream>>>(bsum, boff, nb);
    k_scan_c<<<nb, 256, 0, stream>>>(colStart, boff, N);
    k_fill  <<<(E + 255) / 256, 256, 0, stream>>>(row, col, E, colStart, fillCnt, eSrc);
    k_gather1<<<((size_t)N * 64 + 255) / 256, 256, 0, stream>>>(x, eSrc, colStart, cntC, priv, dis, agg1, N);
    k_mlp_fused<<<(N + 63) / 64, 256, 0, stream>>>(agg1, W1, b1, W2, hp, N);
    k_gather2<<<((size_t)N * 32 + 255) / 256, 256, 0, stream>>>(hp, eSrc, colStart, cntC, dis, b2, out, N);
}

// Round 4
// 247.898 us; speedup vs baseline: 1.8342x; 1.2279x over previous
//
#include <hip/hip_runtime.h>
#include <math.h>

// DP-GCN constants (EPS=1, ALPHA=0.5, DELTA=1):
//   transformed = ((e+1)*x - 1) * (1/(e-1)) + 0.5 = C1*x + C0
#define C1 2.163953413738653f
#define C0 -0.081976706869326f

__global__ void k_zero2(int* __restrict__ a, int* __restrict__ b, int n) {
    int i = blockIdx.x * blockDim.x + threadIdx.x;
    if (i < n) { a[i] = 0; b[i] = 0; }
}

// merged histogram + rank: after this pass cntC[i] == in-degree(i),
// rank[e] == this edge's slot within its col bucket.
__global__ void k_count_rank(const int* __restrict__ row, const int* __restrict__ col, int E,
                             int* __restrict__ degR, int* __restrict__ cntC,
                             int* __restrict__ rank) {
    int e = blockIdx.x * blockDim.x + threadIdx.x;
    if (e < E) {
        atomicAdd(&degR[row[e]], 1);
        rank[e] = atomicAdd(&cntC[col[e]], 1);
    }
}

__global__ void k_dis(const int* __restrict__ degR, float* __restrict__ dis, int n) {
    int i = blockIdx.x * blockDim.x + threadIdx.x;
    if (i < n) dis[i] = rsqrtf((float)(degR[i] + 1));   // +1 self loop
}

// ---- 2-level exclusive scan of cntC -> colStart ----
__global__ void k_scan_a(const int* __restrict__ cnt, int* __restrict__ excl,
                         int* __restrict__ bsum, int n) {
    __shared__ int s[256];
    int idx = blockIdx.x * 256 + threadIdx.x;
    int v = (idx < n) ? cnt[idx] : 0;
    s[threadIdx.x] = v;
    __syncthreads();
    for (int off = 1; off < 256; off <<= 1) {
        int t = (threadIdx.x >= off) ? s[threadIdx.x - off] : 0;
        __syncthreads();
        s[threadIdx.x] += t;
        __syncthreads();
    }
    if (idx < n) excl[idx] = s[threadIdx.x] - v;
    if (threadIdx.x == 255) bsum[blockIdx.x] = s[255];
}

__global__ void k_scan_b(const int* __restrict__ bsum, int* __restrict__ boff, int nb) {
    __shared__ int s[256];
    int v = (threadIdx.x < nb) ? bsum[threadIdx.x] : 0;
    s[threadIdx.x] = v;
    __syncthreads();
    for (int off = 1; off < 256; off <<= 1) {
        int t = (threadIdx.x >= off) ? s[threadIdx.x - off] : 0;
        __syncthreads();
        s[threadIdx.x] += t;
        __syncthreads();
    }
    if (threadIdx.x < nb) boff[threadIdx.x] = s[threadIdx.x] - v;
}

__global__ void k_scan_c(int* __restrict__ excl, const int* __restrict__ boff, int n) {
    int idx = blockIdx.x * 256 + threadIdx.x;
    if (idx < n) excl[idx] += boff[blockIdx.x];
}

// atomic-free CSR fill: one plain 8B store per edge.
// edata[pos] = { (row<<1)|priv[row], bits(dis[row]) }
__global__ void k_fill2(const int* __restrict__ row, const int* __restrict__ col,
                        const int* __restrict__ rank, int E,
                        const int* __restrict__ colStart, const int* __restrict__ priv,
                        const float* __restrict__ dis, int2* __restrict__ edata) {
    int e = blockIdx.x * blockDim.x + threadIdx.x;
    if (e < E) {
        int c = col[e], r = row[e];
        int pos = colStart[c] + rank[e];
        edata[pos] = make_int2((r << 1) | (priv[r] != 0), __float_as_int(dis[r]));
    }
}

// conv1 aggregation by gather: one 64-lane wave per destination node, 4x unrolled
__global__ __launch_bounds__(256) void k_gather1(const float* __restrict__ x,
                                                 const int2* __restrict__ edata,
                                                 const int* __restrict__ colStart,
                                                 const int* __restrict__ cntC,
                                                 const int* __restrict__ priv,
                                                 const float* __restrict__ dis,
                                                 float* __restrict__ agg1, int N) {
    int t = blockIdx.x * blockDim.x + threadIdx.x;
    int c = t >> 6, d = t & 63;
    if (c >= N) return;
    float dc = dis[c];
    float xv = x[(size_t)c * 64 + d];
    float s = dc * (priv[c] ? fmaf(C1, xv, C0) : xv);
    int start = colStart[c], cnt = cntC[c];
    for (int base = 0; base < cnt; base += 64) {
        int m = min(cnt - base, 64);
        int2 ed = (d < m) ? edata[start + base + d] : make_int2(0, 0);
        int k = 0;
        for (; k + 4 <= m; k += 4) {
            int pk0 = __shfl(ed.x, k),     pk1 = __shfl(ed.x, k + 1);
            int pk2 = __shfl(ed.x, k + 2), pk3 = __shfl(ed.x, k + 3);
            float w0 = __int_as_float(__shfl(ed.y, k));
            float w1 = __int_as_float(__shfl(ed.y, k + 1));
            float w2 = __int_as_float(__shfl(ed.y, k + 2));
            float w3 = __int_as_float(__shfl(ed.y, k + 3));
            float x0 = x[(size_t)(pk0 >> 1) * 64 + d];
            float x1 = x[(size_t)(pk1 >> 1) * 64 + d];
            float x2 = x[(size_t)(pk2 >> 1) * 64 + d];
            float x3 = x[(size_t)(pk3 >> 1) * 64 + d];
            float t0 = (pk0 & 1) ? fmaf(C1, x0, C0) : x0;
            float t1 = (pk1 & 1) ? fmaf(C1, x1, C0) : x1;
            float t2 = (pk2 & 1) ? fmaf(C1, x2, C0) : x2;
            float t3 = (pk3 & 1) ? fmaf(C1, x3, C0) : x3;
            s = fmaf(w0, t0, s); s = fmaf(w1, t1, s);
            s = fmaf(w2, t2, s); s = fmaf(w3, t3, s);
        }
        for (; k < m; ++k) {
            int pk = __shfl(ed.x, k);
            float w = __int_as_float(__shfl(ed.y, k));
            float xr = x[(size_t)(pk >> 1) * 64 + d];
            float tr = (pk & 1) ? fmaf(C1, xr, C0) : xr;
            s = fmaf(w, tr, s);
        }
    }
    agg1[(size_t)c * 64 + d] = dc * s;
}

// fused MLP: hp = relu(agg1 @ W1 + b1) @ W2, one 64-node tile per block.
__global__ __launch_bounds__(256) void k_mlp_fused(const float* __restrict__ agg1,
                                                   const float* __restrict__ W1,
                                                   const float* __restrict__ b1,
                                                   const float* __restrict__ W2,
                                                   float* __restrict__ hp, int N) {
    __shared__ float hidT[128 * 68];        // 34816 B; As = rows 0..63
    __shared__ float W2s[128 * 32];         // 16 KB
    float* As = hidT;
    const int t = threadIdx.x;
    const int base = blockIdx.x * 64;

    for (int i = t * 4; i < 128 * 32; i += 1024)
        *(float4*)&W2s[i] = *(const float4*)&W2[i];

    {
        int kq = t & 15, mm = t >> 4;
        #pragma unroll
        for (int p = 0; p < 4; ++p) {
            int m = mm + p * 16;
            int node = base + m;
            if (node >= N) node = N - 1;
            const float4 v = *(const float4*)&agg1[(size_t)node * 64 + kq * 4];
            As[(kq * 4 + 0) * 68 + m] = v.x;
            As[(kq * 4 + 1) * 68 + m] = v.y;
            As[(kq * 4 + 2) * 68 + m] = v.z;
            As[(kq * 4 + 3) * 68 + m] = v.w;
        }
    }
    __syncthreads();

    const int tn = t & 31;
    const int tm = t >> 5;
    float4 bv = *(const float4*)&b1[tn * 4];
    float acc[8][4];
    #pragma unroll
    for (int i = 0; i < 8; ++i) {
        acc[i][0] = bv.x; acc[i][1] = bv.y; acc[i][2] = bv.z; acc[i][3] = bv.w;
    }
    #pragma unroll 4
    for (int k = 0; k < 64; ++k) {
        float4 w  = *(const float4*)&W1[k * 128 + tn * 4];
        float4 a0 = *(const float4*)&As[k * 68 + tm * 8];
        float4 a1 = *(const float4*)&As[k * 68 + tm * 8 + 4];
        const float av[8] = {a0.x, a0.y, a0.z, a0.w, a1.x, a1.y, a1.z, a1.w};
        #pragma unroll
        for (int i = 0; i < 8; ++i) {
            acc[i][0] = fmaf(av[i], w.x, acc[i][0]);
            acc[i][1] = fmaf(av[i], w.y, acc[i][1]);
            acc[i][2] = fmaf(av[i], w.z, acc[i][2]);
            acc[i][3] = fmaf(av[i], w.w, acc[i][3]);
        }
    }
    __syncthreads();

    #pragma unroll
    for (int j = 0; j < 4; ++j)
        #pragma unroll
        for (int i = 0; i < 8; ++i)
            hidT[(tn * 4 + j) * 68 + tm * 8 + i] = fmaxf(acc[i][j], 0.f);
    __syncthreads();

    const int to  = t & 15;
    const int tm2 = t >> 4;
    float o0[4] = {0.f, 0.f, 0.f, 0.f};
    float o1[4] = {0.f, 0.f, 0.f, 0.f};
    #pragma unroll 4
    for (int kh = 0; kh < 128; ++kh) {
        float4 a = *(const float4*)&hidT[kh * 68 + tm2 * 4];
        float2 w = *(const float2*)&W2s[kh * 32 + to * 2];
        const float av[4] = {a.x, a.y, a.z, a.w};
        #pragma unroll
        for (int i = 0; i < 4; ++i) {
            o0[i] = fmaf(av[i], w.x, o0[i]);
            o1[i] = fmaf(av[i], w.y, o1[i]);
        }
    }
    #pragma unroll
    for (int i = 0; i < 4; ++i) {
        int node = base + tm2 * 4 + i;
        if (node < N)
            *(float2*)&hp[(size_t)node * 32 + to * 2] = make_float2(o0[i], o1[i]);
    }
}

// conv2 aggregation by gather: 32 lanes per destination node, 4x unrolled
__global__ __launch_bounds__(256) void k_gather2(const float* __restrict__ hp,
                                                 const int2* __restrict__ edata,
                                                 const int* __restrict__ colStart,
                                                 const int* __restrict__ cntC,
                                                 const float* __restrict__ dis,
                                                 const float* __restrict__ b2,
                                                 float* __restrict__ out, int N) {
    int t = blockIdx.x * blockDim.x + threadIdx.x;
    int c = t >> 5, j = t & 31;
    if (c >= N) return;
    float dc = dis[c];
    float s = dc * hp[(size_t)c * 32 + j];   // self loop
    int start = colStart[c], cnt = cntC[c];
    for (int base = 0; base < cnt; base += 32) {
        int m = min(cnt - base, 32);
        int2 ed = (j < m) ? edata[start + base + j] : make_int2(0, 0);
        int k = 0;
        for (; k + 4 <= m; k += 4) {
            int pk0 = __shfl(ed.x, k, 32),     pk1 = __shfl(ed.x, k + 1, 32);
            int pk2 = __shfl(ed.x, k + 2, 32), pk3 = __shfl(ed.x, k + 3, 32);
            float w0 = __int_as_float(__shfl(ed.y, k, 32));
            float w1 = __int_as_float(__shfl(ed.y, k + 1, 32));
            float w2 = __int_as_float(__shfl(ed.y, k + 2, 32));
            float w3 = __int_as_float(__shfl(ed.y, k + 3, 32));
            float h0 = hp[(size_t)(pk0 >> 1) * 32 + j];
            float h1 = hp[(size_t)(pk1 >> 1) * 32 + j];
            float h2 = hp[(size_t)(pk2 >> 1) * 32 + j];
            float h3 = hp[(size_t)(pk3 >> 1) * 32 + j];
            s = fmaf(w0, h0, s); s = fmaf(w1, h1, s);
            s = fmaf(w2, h2, s); s = fmaf(w3, h3, s);
        }
        for (; k < m; ++k) {
            int pk = __shfl(ed.x, k, 32);
            float w = __int_as_float(__shfl(ed.y, k, 32));
            s = fmaf(w, hp[(size_t)(pk >> 1) * 32 + j], s);
        }
    }
    out[(size_t)c * 32 + j] = b2[j] - dc * s;   // msg2 = -norm*h[row]
}

extern "C" void kernel_launch(void* const* d_in, const int* in_sizes, int n_in,
                              void* d_out, int out_size, void* d_ws, size_t ws_size,
                              hipStream_t stream) {
    const float* x    = (const float*)d_in[0];
    const int*   ei   = (const int*)d_in[1];
    const int*   priv = (const int*)d_in[2];
    const float* W1   = (const float*)d_in[3];
    const float* b1   = (const float*)d_in[4];
    const float* W2   = (const float*)d_in[5];
    const float* b2   = (const float*)d_in[6];
    float* out = (float*)d_out;

    const int N = in_sizes[2];
    const int E = in_sizes[1] / 2;
    const int* row = ei;
    const int* col = ei + E;

    char* ws = (char*)d_ws;
    size_t off = 0;
    auto take = [&](size_t bytes) { char* p = ws + off; off = (off + bytes + 255) & ~(size_t)255; return p; };
    int*   degR     = (int*)  take((size_t)N * 4);
    int*   cntC     = (int*)  take((size_t)N * 4);
    int*   colStart = (int*)  take((size_t)N * 4);
    float* dis      = (float*)take((size_t)N * 4);
    int*   bsum     = (int*)  take(256 * 4);
    int*   boff     = (int*)  take(256 * 4);
    int*   rank     = (int*)  take((size_t)E * 4);
    int2*  edata    = (int2*) take((size_t)E * 8);
    float* agg1     = (float*)take((size_t)N * 64 * 4);
    float* hp       = (float*)take((size_t)N * 32 * 4);
    (void)ws_size;

    const int nb = (N + 255) / 256;

    k_zero2     <<<nb, 256, 0, stream>>>(degR, cntC, N);
    k_count_rank<<<(E + 255) / 256, 256, 0, stream>>>(row, col, E, degR, cntC, rank);
    k_dis       <<<nb, 256, 0, stream>>>(degR, dis, N);
    k_scan_a    <<<nb, 256, 0, stream>>>(cntC, colStart, bsum, N);
    k_scan_b    <<<1, 256, 0, stream>>>(bsum, boff, nb);
    k_scan_c    <<<nb, 256, 0, stream>>>(colStart, boff, N);
    k_fill2     <<<(E + 255) / 256, 256, 0, stream>>>(row, col, rank, E, colStart, priv, dis, edata);
    k_gather1   <<<((size_t)N * 64 + 255) / 256, 256, 0, stream>>>(x, edata, colStart, cntC, priv, dis, agg1, N);
    k_mlp_fused <<<(N + 63) / 64, 256, 0, stream>>>(agg1, W1, b1, W2, hp, N);
    k_gather2   <<<((size_t)N * 32 + 255) / 256, 256, 0, stream>>>(hp, edata, colStart, cntC, dis, b2, out, N);
}

// Round 5
// 246.561 us; speedup vs baseline: 1.8441x; 1.0054x over previous
//
#include <hip/hip_runtime.h>
#include <math.h>

// DP-GCN constants (EPS=1, ALPHA=0.5, DELTA=1):
//   transformed = ((e+1)*x - 1) * (1/(e-1)) + 0.5 = C1*x + C0
#define C1 2.163953413738653f
#define C0 -0.081976706869326f

__global__ void k_zero2(int* __restrict__ a, int* __restrict__ b, int n) {
    int i = blockIdx.x * blockDim.x + threadIdx.x;
    if (i < n) { a[i] = 0; b[i] = 0; }
}

// merged histogram + rank, 4 edges/thread for atomic-latency hiding
__global__ void k_count_rank4(const int* __restrict__ row, const int* __restrict__ col, int E,
                              int* __restrict__ degR, int* __restrict__ cntC,
                              int* __restrict__ rank) {
    int i = blockIdx.x * blockDim.x + threadIdx.x;
    int e = i * 4;
    if (e + 4 <= E) {
        int4 r4 = ((const int4*)row)[i];
        int4 c4 = ((const int4*)col)[i];
        atomicAdd(&degR[r4.x], 1);
        atomicAdd(&degR[r4.y], 1);
        atomicAdd(&degR[r4.z], 1);
        atomicAdd(&degR[r4.w], 1);
        int4 k4;
        k4.x = atomicAdd(&cntC[c4.x], 1);
        k4.y = atomicAdd(&cntC[c4.y], 1);
        k4.z = atomicAdd(&cntC[c4.z], 1);
        k4.w = atomicAdd(&cntC[c4.w], 1);
        ((int4*)rank)[i] = k4;
    } else {
        for (int k = e; k < E; ++k) {
            atomicAdd(&degR[row[k]], 1);
            rank[k] = atomicAdd(&cntC[col[k]], 1);
        }
    }
}

// ---- 2-level exclusive scan of cntC -> colStart ----
__global__ void k_scan_a(const int* __restrict__ cnt, int* __restrict__ excl,
                         int* __restrict__ bsum, int n) {
    __shared__ int s[256];
    int idx = blockIdx.x * 256 + threadIdx.x;
    int v = (idx < n) ? cnt[idx] : 0;
    s[threadIdx.x] = v;
    __syncthreads();
    for (int off = 1; off < 256; off <<= 1) {
        int t = (threadIdx.x >= off) ? s[threadIdx.x - off] : 0;
        __syncthreads();
        s[threadIdx.x] += t;
        __syncthreads();
    }
    if (idx < n) excl[idx] = s[threadIdx.x] - v;
    if (threadIdx.x == 255) bsum[blockIdx.x] = s[255];
}

__global__ void k_scan_b(const int* __restrict__ bsum, int* __restrict__ boff, int nb) {
    __shared__ int s[256];
    int v = (threadIdx.x < nb) ? bsum[threadIdx.x] : 0;
    s[threadIdx.x] = v;
    __syncthreads();
    for (int off = 1; off < 256; off <<= 1) {
        int t = (threadIdx.x >= off) ? s[threadIdx.x - off] : 0;
        __syncthreads();
        s[threadIdx.x] += t;
        __syncthreads();
    }
    if (threadIdx.x < nb) boff[threadIdx.x] = s[threadIdx.x] - v;
}

// scan finalize + dis + packed nodeinfo  (nodeinfo[i] = {(i<<1)|priv, bits(dis[i])})
__global__ void k_scan_c_dis(int* __restrict__ excl, const int* __restrict__ boff,
                             const int* __restrict__ degR, const int* __restrict__ priv,
                             float* __restrict__ dis, int2* __restrict__ nodeinfo, int n) {
    int idx = blockIdx.x * 256 + threadIdx.x;
    if (idx < n) {
        excl[idx] += boff[blockIdx.x];
        float dv = rsqrtf((float)(degR[idx] + 1));   // +1 self loop
        dis[idx] = dv;
        nodeinfo[idx] = make_int2((idx << 1) | (priv[idx] != 0), __float_as_int(dv));
    }
}

// atomic-free CSR fill, 4 edges/thread: edata[pos] = nodeinfo[row]
__global__ void k_fill4(const int* __restrict__ row, const int* __restrict__ col,
                        const int* __restrict__ rank, int E,
                        const int* __restrict__ colStart,
                        const int2* __restrict__ nodeinfo, int2* __restrict__ edata) {
    int i = blockIdx.x * blockDim.x + threadIdx.x;
    int e = i * 4;
    if (e + 4 <= E) {
        int4 r4 = ((const int4*)row)[i];
        int4 c4 = ((const int4*)col)[i];
        int4 k4 = ((const int4*)rank)[i];
        int s0 = colStart[c4.x], s1 = colStart[c4.y];
        int s2 = colStart[c4.z], s3 = colStart[c4.w];
        int2 n0 = nodeinfo[r4.x], n1 = nodeinfo[r4.y];
        int2 n2 = nodeinfo[r4.z], n3 = nodeinfo[r4.w];
        edata[s0 + k4.x] = n0;
        edata[s1 + k4.y] = n1;
        edata[s2 + k4.z] = n2;
        edata[s3 + k4.w] = n3;
    } else {
        for (int k = e; k < E; ++k) {
            int c = col[k], r = row[k];
            edata[colStart[c] + rank[k]] = nodeinfo[r];
        }
    }
}

// conv1 aggregation by gather: one 64-lane wave per destination node, 4x unrolled
__global__ __launch_bounds__(256) void k_gather1(const float* __restrict__ x,
                                                 const int2* __restrict__ edata,
                                                 const int* __restrict__ colStart,
                                                 const int* __restrict__ cntC,
                                                 const int* __restrict__ priv,
                                                 const float* __restrict__ dis,
                                                 float* __restrict__ agg1, int N) {
    int t = blockIdx.x * blockDim.x + threadIdx.x;
    int c = t >> 6, d = t & 63;
    if (c >= N) return;
    float dc = dis[c];
    float xv = x[(size_t)c * 64 + d];
    float s = dc * (priv[c] ? fmaf(C1, xv, C0) : xv);
    int start = colStart[c], cnt = cntC[c];
    for (int base = 0; base < cnt; base += 64) {
        int m = min(cnt - base, 64);
        int2 ed = (d < m) ? edata[start + base + d] : make_int2(0, 0);
        int k = 0;
        for (; k + 4 <= m; k += 4) {
            int pk0 = __shfl(ed.x, k),     pk1 = __shfl(ed.x, k + 1);
            int pk2 = __shfl(ed.x, k + 2), pk3 = __shfl(ed.x, k + 3);
            float w0 = __int_as_float(__shfl(ed.y, k));
            float w1 = __int_as_float(__shfl(ed.y, k + 1));
            float w2 = __int_as_float(__shfl(ed.y, k + 2));
            float w3 = __int_as_float(__shfl(ed.y, k + 3));
            float x0 = x[(size_t)(pk0 >> 1) * 64 + d];
            float x1 = x[(size_t)(pk1 >> 1) * 64 + d];
            float x2 = x[(size_t)(pk2 >> 1) * 64 + d];
            float x3 = x[(size_t)(pk3 >> 1) * 64 + d];
            float t0 = (pk0 & 1) ? fmaf(C1, x0, C0) : x0;
            float t1 = (pk1 & 1) ? fmaf(C1, x1, C0) : x1;
            float t2 = (pk2 & 1) ? fmaf(C1, x2, C0) : x2;
            float t3 = (pk3 & 1) ? fmaf(C1, x3, C0) : x3;
            s = fmaf(w0, t0, s); s = fmaf(w1, t1, s);
            s = fmaf(w2, t2, s); s = fmaf(w3, t3, s);
        }
        for (; k < m; ++k) {
            int pk = __shfl(ed.x, k);
            float w = __int_as_float(__shfl(ed.y, k));
            float xr = x[(size_t)(pk >> 1) * 64 + d];
            float tr = (pk & 1) ? fmaf(C1, xr, C0) : xr;
            s = fmaf(w, tr, s);
        }
    }
    agg1[(size_t)c * 64 + d] = dc * s;
}

// fused MLP: hp = relu(agg1 @ W1 + b1) @ W2, one 64-node tile per block.
__global__ __launch_bounds__(256) void k_mlp_fused(const float* __restrict__ agg1,
                                                   const float* __restrict__ W1,
                                                   const float* __restrict__ b1,
                                                   const float* __restrict__ W2,
                                                   float* __restrict__ hp, int N) {
    __shared__ float hidT[128 * 68];        // 34816 B; As = rows 0..63
    __shared__ float W2s[128 * 32];         // 16 KB
    float* As = hidT;
    const int t = threadIdx.x;
    const int base = blockIdx.x * 64;

    for (int i = t * 4; i < 128 * 32; i += 1024)
        *(float4*)&W2s[i] = *(const float4*)&W2[i];

    {
        int kq = t & 15, mm = t >> 4;
        #pragma unroll
        for (int p = 0; p < 4; ++p) {
            int m = mm + p * 16;
            int node = base + m;
            if (node >= N) node = N - 1;
            const float4 v = *(const float4*)&agg1[(size_t)node * 64 + kq * 4];
            As[(kq * 4 + 0) * 68 + m] = v.x;
            As[(kq * 4 + 1) * 68 + m] = v.y;
            As[(kq * 4 + 2) * 68 + m] = v.z;
            As[(kq * 4 + 3) * 68 + m] = v.w;
        }
    }
    __syncthreads();

    const int tn = t & 31;
    const int tm = t >> 5;
    float4 bv = *(const float4*)&b1[tn * 4];
    float acc[8][4];
    #pragma unroll
    for (int i = 0; i < 8; ++i) {
        acc[i][0] = bv.x; acc[i][1] = bv.y; acc[i][2] = bv.z; acc[i][3] = bv.w;
    }
    #pragma unroll 4
    for (int k = 0; k < 64; ++k) {
        float4 w  = *(const float4*)&W1[k * 128 + tn * 4];
        float4 a0 = *(const float4*)&As[k * 68 + tm * 8];
        float4 a1 = *(const float4*)&As[k * 68 + tm * 8 + 4];
        const float av[8] = {a0.x, a0.y, a0.z, a0.w, a1.x, a1.y, a1.z, a1.w};
        #pragma unroll
        for (int i = 0; i < 8; ++i) {
            acc[i][0] = fmaf(av[i], w.x, acc[i][0]);
            acc[i][1] = fmaf(av[i], w.y, acc[i][1]);
            acc[i][2] = fmaf(av[i], w.z, acc[i][2]);
            acc[i][3] = fmaf(av[i], w.w, acc[i][3]);
        }
    }
    __syncthreads();

    #pragma unroll
    for (int j = 0; j < 4; ++j)
        #pragma unroll
        for (int i = 0; i < 8; ++i)
            hidT[(tn * 4 + j) * 68 + tm * 8 + i] = fmaxf(acc[i][j], 0.f);
    __syncthreads();

    const int to  = t & 15;
    const int tm2 = t >> 4;
    float o0[4] = {0.f, 0.f, 0.f, 0.f};
    float o1[4] = {0.f, 0.f, 0.f, 0.f};
    #pragma unroll 4
    for (int kh = 0; kh < 128; ++kh) {
        float4 a = *(const float4*)&hidT[kh * 68 + tm2 * 4];
        float2 w = *(const float2*)&W2s[kh * 32 + to * 2];
        const float av[4] = {a.x, a.y, a.z, a.w};
        #pragma unroll
        for (int i = 0; i < 4; ++i) {
            o0[i] = fmaf(av[i], w.x, o0[i]);
            o1[i] = fmaf(av[i], w.y, o1[i]);
        }
    }
    #pragma unroll
    for (int i = 0; i < 4; ++i) {
        int node = base + tm2 * 4 + i;
        if (node < N)
            *(float2*)&hp[(size_t)node * 32 + to * 2] = make_float2(o0[i], o1[i]);
    }
}

// conv2 aggregation by gather: 32 lanes per destination node, 4x unrolled
__global__ __launch_bounds__(256) void k_gather2(const float* __restrict__ hp,
                                                 const int2* __restrict__ edata,
                                                 const int* __restrict__ colStart,
                                                 const int* __restrict__ cntC,
                                                 const float* __restrict__ dis,
                                                 const float* __restrict__ b2,
                                                 float* __restrict__ out, int N) {
    int t = blockIdx.x * blockDim.x + threadIdx.x;
    int c = t >> 5, j = t & 31;
    if (c >= N) return;
    float dc = dis[c];
    float s = dc * hp[(size_t)c * 32 + j];   // self loop
    int start = colStart[c], cnt = cntC[c];
    for (int base = 0; base < cnt; base += 32) {
        int m = min(cnt - base, 32);
        int2 ed = (j < m) ? edata[start + base + j] : make_int2(0, 0);
        int k = 0;
        for (; k + 4 <= m; k += 4) {
            int pk0 = __shfl(ed.x, k, 32),     pk1 = __shfl(ed.x, k + 1, 32);
            int pk2 = __shfl(ed.x, k + 2, 32), pk3 = __shfl(ed.x, k + 3, 32);
            float w0 = __int_as_float(__shfl(ed.y, k, 32));
            float w1 = __int_as_float(__shfl(ed.y, k + 1, 32));
            float w2 = __int_as_float(__shfl(ed.y, k + 2, 32));
            float w3 = __int_as_float(__shfl(ed.y, k + 3, 32));
            float h0 = hp[(size_t)(pk0 >> 1) * 32 + j];
            float h1 = hp[(size_t)(pk1 >> 1) * 32 + j];
            float h2 = hp[(size_t)(pk2 >> 1) * 32 + j];
            float h3 = hp[(size_t)(pk3 >> 1) * 32 + j];
            s = fmaf(w0, h0, s); s = fmaf(w1, h1, s);
            s = fmaf(w2, h2, s); s = fmaf(w3, h3, s);
        }
        for (; k < m; ++k) {
            int pk = __shfl(ed.x, k, 32);
            float w = __int_as_float(__shfl(ed.y, k, 32));
            s = fmaf(w, hp[(size_t)(pk >> 1) * 32 + j], s);
        }
    }
    out[(size_t)c * 32 + j] = b2[j] - dc * s;   // msg2 = -norm*h[row]
}

extern "C" void kernel_launch(void* const* d_in, const int* in_sizes, int n_in,
                              void* d_out, int out_size, void* d_ws, size_t ws_size,
                              hipStream_t stream) {
    const float* x    = (const float*)d_in[0];
    const int*   ei   = (const int*)d_in[1];
    const int*   priv = (const int*)d_in[2];
    const float* W1   = (const float*)d_in[3];
    const float* b1   = (const float*)d_in[4];
    const float* W2   = (const float*)d_in[5];
    const float* b2   = (const float*)d_in[6];
    float* out = (float*)d_out;

    const int N = in_sizes[2];
    const int E = in_sizes[1] / 2;
    const int* row = ei;
    const int* col = ei + E;

    char* ws = (char*)d_ws;
    size_t off = 0;
    auto take = [&](size_t bytes) { char* p = ws + off; off = (off + bytes + 255) & ~(size_t)255; return p; };
    int*   degR     = (int*)  take((size_t)N * 4);
    int*   cntC     = (int*)  take((size_t)N * 4);
    int*   colStart = (int*)  take((size_t)N * 4);
    float* dis      = (float*)take((size_t)N * 4);
    int2*  nodeinfo = (int2*) take((size_t)N * 8);
    int*   bsum     = (int*)  take(256 * 4);
    int*   boff     = (int*)  take(256 * 4);
    int*   rank     = (int*)  take((size_t)E * 4);
    int2*  edata    = (int2*) take((size_t)E * 8);
    float* agg1     = (float*)take((size_t)N * 64 * 4);
    float* hp       = (float*)take((size_t)N * 32 * 4);
    (void)ws_size;

    const int nb = (N + 255) / 256;
    const int nbE4 = ((E + 3) / 4 + 255) / 256;

    k_zero2      <<<nb, 256, 0, stream>>>(degR, cntC, N);
    k_count_rank4<<<nbE4, 256, 0, stream>>>(row, col, E, degR, cntC, rank);
    k_scan_a     <<<nb, 256, 0, stream>>>(cntC, colStart, bsum, N);
    k_scan_b     <<<1, 256, 0, stream>>>(bsum, boff, nb);
    k_scan_c_dis <<<nb, 256, 0, stream>>>(colStart, boff, degR, priv, dis, nodeinfo, N);
    k_fill4      <<<nbE4, 256, 0, stream>>>(row, col, rank, E, colStart, nodeinfo, edata);
    k_gather1    <<<((size_t)N * 64 + 255) / 256, 256, 0, stream>>>(x, edata, colStart, cntC, priv, dis, agg1, N);
    k_mlp_fused  <<<(N + 63) / 64, 256, 0, stream>>>(agg1, W1, b1, W2, hp, N);
    k_gather2    <<<((size_t)N * 32 + 255) / 256, 256, 0, stream>>>(hp, edata, colStart, cntC, dis, b2, out, N);
}

// Round 6
// 193.821 us; speedup vs baseline: 2.3459x; 1.2721x over previous
//
#include <hip/hip_runtime.h>
#include <math.h>

// DP-GCN constants (EPS=1, ALPHA=0.5, DELTA=1):
//   transformed = ((e+1)*x - 1) * (1/(e-1)) + 0.5 = C1*x + C0
#define C1 2.163953413738653f
#define C0 -0.081976706869326f

// NOTE: assumes N <= 65536 so node ids pack into 16 bits (N=50000 here).

// ---- dual per-block histogram of col>>8 and row>>8 (LDS atomics only) ----
// hist layout: [d*256 + b] for cols, [65536 + d*256 + b] for rows; gridDim MUST be 256.
__global__ __launch_bounds__(1024) void k_hist2(const int* __restrict__ row,
                                                const int* __restrict__ col, int E, int chunk,
                                                int* __restrict__ hist) {
    __shared__ int hc[256], hr[256];
    int t = threadIdx.x, b = blockIdx.x;
    if (t < 256) { hc[t] = 0; hr[t] = 0; }
    __syncthreads();
    int lo = b * chunk, hi = min(E, lo + chunk);
    for (int i = lo + t; i < hi; i += 1024) {
        atomicAdd(&hc[col[i] >> 8], 1);
        atomicAdd(&hr[row[i] >> 8], 1);
    }
    __syncthreads();
    if (t < 256) {
        hist[t * 256 + b] = hc[t];
        hist[65536 + t * 256 + b] = hr[t];
    }
}

// ---- 2-level exclusive scan over 131072 counts ----
__global__ void k_scan_a(const int* __restrict__ cnt, int* __restrict__ excl,
                         int* __restrict__ bsum, int n) {
    __shared__ int s[256];
    int idx = blockIdx.x * 256 + threadIdx.x;
    int v = (idx < n) ? cnt[idx] : 0;
    s[threadIdx.x] = v;
    __syncthreads();
    for (int off = 1; off < 256; off <<= 1) {
        int t = (threadIdx.x >= off) ? s[threadIdx.x - off] : 0;
        __syncthreads();
        s[threadIdx.x] += t;
        __syncthreads();
    }
    if (idx < n) excl[idx] = s[threadIdx.x] - v;
    if (threadIdx.x == 255) bsum[blockIdx.x] = s[255];
}

__global__ void k_scan_b512(const int* __restrict__ bsum, int* __restrict__ boff, int nb) {
    __shared__ int s[512];
    int t = threadIdx.x;
    int v = (t < nb) ? bsum[t] : 0;
    s[t] = v;
    __syncthreads();
    for (int off = 1; off < 512; off <<= 1) {
        int u = (t >= off) ? s[t - off] : 0;
        __syncthreads();
        s[t] += u;
        __syncthreads();
    }
    if (t < nb) boff[t] = s[t] - v;
}

__global__ void k_scan_c(int* __restrict__ excl, const int* __restrict__ boff, int n) {
    int idx = blockIdx.x * 256 + threadIdx.x;
    if (idx < n) excl[idx] += boff[blockIdx.x];
}

// ---- partition edges by col>>8 (cbuf) and rows by row>>8 (rbuf); plain stores ----
__global__ __launch_bounds__(1024) void k_part(const int* __restrict__ row,
                                               const int* __restrict__ col, int E, int chunk,
                                               const int* __restrict__ shist,
                                               unsigned* __restrict__ cbuf,
                                               int* __restrict__ rbuf) {
    __shared__ int offc[256], offr[256];
    int t = threadIdx.x, b = blockIdx.x;
    if (t < 256) {
        offc[t] = shist[t * 256 + b];
        offr[t] = shist[65536 + t * 256 + b] - E;
    }
    __syncthreads();
    int lo = b * chunk, hi = min(E, lo + chunk);
    for (int i = lo + t; i < hi; i += 1024) {
        int r = row[i], c = col[i];
        int pc = atomicAdd(&offc[c >> 8], 1);
        cbuf[pc] = ((unsigned)c << 16) | (unsigned)r;
        int pr = atomicAdd(&offr[r >> 8], 1);
        rbuf[pr] = r;
    }
}

// ---- per row-bucket: exact degree + dis + packed nodeinfo ----
__global__ __launch_bounds__(256) void k_deg2(const int* __restrict__ rbuf,
                                              const int* __restrict__ shist,
                                              const int* __restrict__ priv, int N, int E,
                                              float* __restrict__ dis,
                                              int2* __restrict__ nodeinfo) {
    __shared__ int cnt[256];
    int t = threadIdx.x, b = blockIdx.x;
    cnt[t] = 0;
    __syncthreads();
    int rs = shist[65536 + b * 256] - E;
    int re = (b == 255) ? E : (shist[65536 + (b + 1) * 256] - E);
    for (int i = rs + t; i < re; i += 256) atomicAdd(&cnt[rbuf[i] & 255], 1);
    __syncthreads();
    int node = b * 256 + t;
    if (node < N) {
        float dv = rsqrtf((float)(cnt[t] + 1));   // +1 self loop
        dis[node] = dv;
        nodeinfo[node] = make_int2((node << 1) | (priv[node] != 0), __float_as_int(dv));
    }
}

// ---- per col-bucket: cntC/colStart + scatter edata[pos] = nodeinfo[row] ----
__global__ __launch_bounds__(256) void k_csr(const unsigned* __restrict__ cbuf,
                                             const int* __restrict__ shist,
                                             const int2* __restrict__ nodeinfo, int N, int E,
                                             int* __restrict__ cntC, int* __restrict__ colStart,
                                             int2* __restrict__ edata) {
    __shared__ int cnt[256], ls[256], cnt2[256];
    int t = threadIdx.x, b = blockIdx.x;
    cnt[t] = 0; cnt2[t] = 0;
    __syncthreads();
    int cs = shist[b * 256];
    int ce = (b == 255) ? E : shist[(b + 1) * 256];
    for (int i = cs + t; i < ce; i += 256) atomicAdd(&cnt[(cbuf[i] >> 16) & 255], 1);
    __syncthreads();
    int v = cnt[t];
    ls[t] = v;
    __syncthreads();
    for (int off = 1; off < 256; off <<= 1) {
        int u = (t >= off) ? ls[t - off] : 0;
        __syncthreads();
        ls[t] += u;
        __syncthreads();
    }
    int excl = ls[t] - v;
    int c = b * 256 + t;
    if (c < N) { cntC[c] = v; colStart[c] = cs + excl; }
    __syncthreads();
    ls[t] = excl;
    __syncthreads();
    for (int i = cs + t; i < ce; i += 256) {
        unsigned e = cbuf[i];
        int d = (e >> 16) & 255;
        int r = (int)(e & 0xFFFFu);
        int pos = cs + ls[d] + atomicAdd(&cnt2[d], 1);
        edata[pos] = nodeinfo[r];
    }
}

// conv1 aggregation by gather: one 64-lane wave per destination node, 4x unrolled
__global__ __launch_bounds__(256) void k_gather1(const float* __restrict__ x,
                                                 const int2* __restrict__ edata,
                                                 const int* __restrict__ colStart,
                                                 const int* __restrict__ cntC,
                                                 const int* __restrict__ priv,
                                                 const float* __restrict__ dis,
                                                 float* __restrict__ agg1, int N) {
    int t = blockIdx.x * blockDim.x + threadIdx.x;
    int c = t >> 6, d = t & 63;
    if (c >= N) return;
    float dc = dis[c];
    float xv = x[(size_t)c * 64 + d];
    float s = dc * (priv[c] ? fmaf(C1, xv, C0) : xv);
    int start = colStart[c], cnt = cntC[c];
    for (int base = 0; base < cnt; base += 64) {
        int m = min(cnt - base, 64);
        int2 ed = (d < m) ? edata[start + base + d] : make_int2(0, 0);
        int k = 0;
        for (; k + 4 <= m; k += 4) {
            int pk0 = __shfl(ed.x, k),     pk1 = __shfl(ed.x, k + 1);
            int pk2 = __shfl(ed.x, k + 2), pk3 = __shfl(ed.x, k + 3);
            float w0 = __int_as_float(__shfl(ed.y, k));
            float w1 = __int_as_float(__shfl(ed.y, k + 1));
            float w2 = __int_as_float(__shfl(ed.y, k + 2));
            float w3 = __int_as_float(__shfl(ed.y, k + 3));
            float x0 = x[(size_t)(pk0 >> 1) * 64 + d];
            float x1 = x[(size_t)(pk1 >> 1) * 64 + d];
            float x2 = x[(size_t)(pk2 >> 1) * 64 + d];
            float x3 = x[(size_t)(pk3 >> 1) * 64 + d];
            float t0 = (pk0 & 1) ? fmaf(C1, x0, C0) : x0;
            float t1 = (pk1 & 1) ? fmaf(C1, x1, C0) : x1;
            float t2 = (pk2 & 1) ? fmaf(C1, x2, C0) : x2;
            float t3 = (pk3 & 1) ? fmaf(C1, x3, C0) : x3;
            s = fmaf(w0, t0, s); s = fmaf(w1, t1, s);
            s = fmaf(w2, t2, s); s = fmaf(w3, t3, s);
        }
        for (; k < m; ++k) {
            int pk = __shfl(ed.x, k);
            float w = __int_as_float(__shfl(ed.y, k));
            float xr = x[(size_t)(pk >> 1) * 64 + d];
            float tr = (pk & 1) ? fmaf(C1, xr, C0) : xr;
            s = fmaf(w, tr, s);
        }
    }
    agg1[(size_t)c * 64 + d] = dc * s;
}

// fused MLP: hp = relu(agg1 @ W1 + b1) @ W2, one 64-node tile per block.
__global__ __launch_bounds__(256) void k_mlp_fused(const float* __restrict__ agg1,
                                                   const float* __restrict__ W1,
                                                   const float* __restrict__ b1,
                                                   const float* __restrict__ W2,
                                                   float* __restrict__ hp, int N) {
    __shared__ float hidT[128 * 68];        // 34816 B; As = rows 0..63
    __shared__ float W2s[128 * 32];         // 16 KB
    float* As = hidT;
    const int t = threadIdx.x;
    const int base = blockIdx.x * 64;

    for (int i = t * 4; i < 128 * 32; i += 1024)
        *(float4*)&W2s[i] = *(const float4*)&W2[i];

    {
        int kq = t & 15, mm = t >> 4;
        #pragma unroll
        for (int p = 0; p < 4; ++p) {
            int m = mm + p * 16;
            int node = base + m;
            if (node >= N) node = N - 1;
            const float4 v = *(const float4*)&agg1[(size_t)node * 64 + kq * 4];
            As[(kq * 4 + 0) * 68 + m] = v.x;
            As[(kq * 4 + 1) * 68 + m] = v.y;
            As[(kq * 4 + 2) * 68 + m] = v.z;
            As[(kq * 4 + 3) * 68 + m] = v.w;
        }
    }
    __syncthreads();

    const int tn = t & 31;
    const int tm = t >> 5;
    float4 bv = *(const float4*)&b1[tn * 4];
    float acc[8][4];
    #pragma unroll
    for (int i = 0; i < 8; ++i) {
        acc[i][0] = bv.x; acc[i][1] = bv.y; acc[i][2] = bv.z; acc[i][3] = bv.w;
    }
    #pragma unroll 4
    for (int k = 0; k < 64; ++k) {
        float4 w  = *(const float4*)&W1[k * 128 + tn * 4];
        float4 a0 = *(const float4*)&As[k * 68 + tm * 8];
        float4 a1 = *(const float4*)&As[k * 68 + tm * 8 + 4];
        const float av[8] = {a0.x, a0.y, a0.z, a0.w, a1.x, a1.y, a1.z, a1.w};
        #pragma unroll
        for (int i = 0; i < 8; ++i) {
            acc[i][0] = fmaf(av[i], w.x, acc[i][0]);
            acc[i][1] = fmaf(av[i], w.y, acc[i][1]);
            acc[i][2] = fmaf(av[i], w.z, acc[i][2]);
            acc[i][3] = fmaf(av[i], w.w, acc[i][3]);
        }
    }
    __syncthreads();

    #pragma unroll
    for (int j = 0; j < 4; ++j)
        #pragma unroll
        for (int i = 0; i < 8; ++i)
            hidT[(tn * 4 + j) * 68 + tm * 8 + i] = fmaxf(acc[i][j], 0.f);
    __syncthreads();

    const int to  = t & 15;
    const int tm2 = t >> 4;
    float o0[4] = {0.f, 0.f, 0.f, 0.f};
    float o1[4] = {0.f, 0.f, 0.f, 0.f};
    #pragma unroll 4
    for (int kh = 0; kh < 128; ++kh) {
        float4 a = *(const float4*)&hidT[kh * 68 + tm2 * 4];
        float2 w = *(const float2*)&W2s[kh * 32 + to * 2];
        const float av[4] = {a.x, a.y, a.z, a.w};
        #pragma unroll
        for (int i = 0; i < 4; ++i) {
            o0[i] = fmaf(av[i], w.x, o0[i]);
            o1[i] = fmaf(av[i], w.y, o1[i]);
        }
    }
    #pragma unroll
    for (int i = 0; i < 4; ++i) {
        int node = base + tm2 * 4 + i;
        if (node < N)
            *(float2*)&hp[(size_t)node * 32 + to * 2] = make_float2(o0[i], o1[i]);
    }
}

// conv2 aggregation by gather: 32 lanes per destination node, 4x unrolled
__global__ __launch_bounds__(256) void k_gather2(const float* __restrict__ hp,
                                                 const int2* __restrict__ edata,
                                                 const int* __restrict__ colStart,
                                                 const int* __restrict__ cntC,
                                                 const float* __restrict__ dis,
                                                 const float* __restrict__ b2,
                                                 float* __restrict__ out, int N) {
    int t = blockIdx.x * blockDim.x + threadIdx.x;
    int c = t >> 5, j = t & 31;
    if (c >= N) return;
    float dc = dis[c];
    float s = dc * hp[(size_t)c * 32 + j];   // self loop
    int start = colStart[c], cnt = cntC[c];
    for (int base = 0; base < cnt; base += 32) {
        int m = min(cnt - base, 32);
        int2 ed = (j < m) ? edata[start + base + j] : make_int2(0, 0);
        int k = 0;
        for (; k + 4 <= m; k += 4) {
            int pk0 = __shfl(ed.x, k, 32),     pk1 = __shfl(ed.x, k + 1, 32);
            int pk2 = __shfl(ed.x, k + 2, 32), pk3 = __shfl(ed.x, k + 3, 32);
            float w0 = __int_as_float(__shfl(ed.y, k, 32));
            float w1 = __int_as_float(__shfl(ed.y, k + 1, 32));
            float w2 = __int_as_float(__shfl(ed.y, k + 2, 32));
            float w3 = __int_as_float(__shfl(ed.y, k + 3, 32));
            float h0 = hp[(size_t)(pk0 >> 1) * 32 + j];
            float h1 = hp[(size_t)(pk1 >> 1) * 32 + j];
            float h2 = hp[(size_t)(pk2 >> 1) * 32 + j];
            float h3 = hp[(size_t)(pk3 >> 1) * 32 + j];
            s = fmaf(w0, h0, s); s = fmaf(w1, h1, s);
            s = fmaf(w2, h2, s); s = fmaf(w3, h3, s);
        }
        for (; k < m; ++k) {
            int pk = __shfl(ed.x, k, 32);
            float w = __int_as_float(__shfl(ed.y, k, 32));
            s = fmaf(w, hp[(size_t)(pk >> 1) * 32 + j], s);
        }
    }
    out[(size_t)c * 32 + j] = b2[j] - dc * s;   // msg2 = -norm*h[row]
}

extern "C" void kernel_launch(void* const* d_in, const int* in_sizes, int n_in,
                              void* d_out, int out_size, void* d_ws, size_t ws_size,
                              hipStream_t stream) {
    const float* x    = (const float*)d_in[0];
    const int*   ei   = (const int*)d_in[1];
    const int*   priv = (const int*)d_in[2];
    const float* W1   = (const float*)d_in[3];
    const float* b1   = (const float*)d_in[4];
    const float* W2   = (const float*)d_in[5];
    const float* b2   = (const float*)d_in[6];
    float* out = (float*)d_out;

    const int N = in_sizes[2];
    const int E = in_sizes[1] / 2;
    const int* row = ei;
    const int* col = ei + E;

    char* ws = (char*)d_ws;
    size_t off = 0;
    auto take = [&](size_t bytes) { char* p = ws + off; off = (off + bytes + 255) & ~(size_t)255; return p; };
    int*      hist     = (int*)     take((size_t)131072 * 4);
    int*      shist    = (int*)     take((size_t)131072 * 4);
    int*      bsum     = (int*)     take(512 * 4);
    int*      boff     = (int*)     take(512 * 4);
    unsigned* cbuf     = (unsigned*)take((size_t)E * 4);
    int*      rbuf     = (int*)     take((size_t)E * 4);
    float*    dis      = (float*)   take((size_t)N * 4);
    int2*     nodeinfo = (int2*)    take((size_t)N * 8);
    int*      cntC     = (int*)     take((size_t)N * 4);
    int*      colStart = (int*)     take((size_t)N * 4);
    int2*     edata    = (int2*)    take((size_t)E * 8);
    float*    agg1     = (float*)   take((size_t)N * 64 * 4);
    float*    hp       = (float*)   take((size_t)N * 32 * 4);
    (void)ws_size;

    const int chunk = (E + 255) / 256;
    const int nbk = (N + 255) / 256;     // node buckets (196)

    k_hist2   <<<256, 1024, 0, stream>>>(row, col, E, chunk, hist);
    k_scan_a  <<<512, 256, 0, stream>>>(hist, shist, bsum, 131072);
    k_scan_b512<<<1, 512, 0, stream>>>(bsum, boff, 512);
    k_scan_c  <<<512, 256, 0, stream>>>(shist, boff, 131072);
    k_part    <<<256, 1024, 0, stream>>>(row, col, E, chunk, shist, cbuf, rbuf);
    k_deg2    <<<nbk, 256, 0, stream>>>(rbuf, shist, priv, N, E, dis, nodeinfo);
    k_csr     <<<nbk, 256, 0, stream>>>(cbuf, shist, nodeinfo, N, E, cntC, colStart, edata);
    k_gather1 <<<((size_t)N * 64 + 255) / 256, 256, 0, stream>>>(x, edata, colStart, cntC, priv, dis, agg1, N);
    k_mlp_fused<<<(N + 63) / 64, 256, 0, stream>>>(agg1, W1, b1, W2, hp, N);
    k_gather2 <<<((size_t)N * 32 + 255) / 256, 256, 0, stream>>>(hp, edata, colStart, cntC, dis, b2, out, N);
}

// Round 7
// 189.155 us; speedup vs baseline: 2.4038x; 1.0247x over previous
//
#include <hip/hip_runtime.h>
#include <math.h>

// DP-GCN constants (EPS=1, ALPHA=0.5, DELTA=1):
//   transformed = ((e+1)*x - 1) * (1/(e-1)) + 0.5 = C1*x + C0
#define C1 2.163953413738653f
#define C0 -0.081976706869326f

// NOTE: assumes N <= 65536 so node ids fit u16 (N=50000 here).

static __device__ __forceinline__ unsigned short f2bf(float f) {   // RTN-even
    unsigned b = __float_as_uint(f);
    return (unsigned short)((b + 0x7FFFu + ((b >> 16) & 1u)) >> 16);
}
static __device__ __forceinline__ float bf2f(unsigned short u) {
    return __uint_as_float((unsigned)u << 16);
}

// ---- dual per-block histogram of col>>8 and row>>8 (LDS atomics only) ----
__global__ __launch_bounds__(1024) void k_hist2(const int* __restrict__ row,
                                                const int* __restrict__ col, int E, int chunk,
                                                int* __restrict__ hist) {
    __shared__ int hc[256], hr[256];
    int t = threadIdx.x, b = blockIdx.x;
    if (t < 256) { hc[t] = 0; hr[t] = 0; }
    __syncthreads();
    int lo = b * chunk, hi = min(E, lo + chunk);
    for (int i = lo + t; i < hi; i += 1024) {
        atomicAdd(&hc[col[i] >> 8], 1);
        atomicAdd(&hr[row[i] >> 8], 1);
    }
    __syncthreads();
    if (t < 256) {
        hist[t * 256 + b] = hc[t];
        hist[65536 + t * 256 + b] = hr[t];
    }
}

// ---- 2-level exclusive scan over 131072 counts ----
__global__ void k_scan_a(const int* __restrict__ cnt, int* __restrict__ excl,
                         int* __restrict__ bsum, int n) {
    __shared__ int s[256];
    int idx = blockIdx.x * 256 + threadIdx.x;
    int v = (idx < n) ? cnt[idx] : 0;
    s[threadIdx.x] = v;
    __syncthreads();
    for (int off = 1; off < 256; off <<= 1) {
        int t = (threadIdx.x >= off) ? s[threadIdx.x - off] : 0;
        __syncthreads();
        s[threadIdx.x] += t;
        __syncthreads();
    }
    if (idx < n) excl[idx] = s[threadIdx.x] - v;
    if (threadIdx.x == 255) bsum[blockIdx.x] = s[255];
}

__global__ void k_scan_b512(const int* __restrict__ bsum, int* __restrict__ boff, int nb) {
    __shared__ int s[512];
    int t = threadIdx.x;
    int v = (t < nb) ? bsum[t] : 0;
    s[t] = v;
    __syncthreads();
    for (int off = 1; off < 512; off <<= 1) {
        int u = (t >= off) ? s[t - off] : 0;
        __syncthreads();
        s[t] += u;
        __syncthreads();
    }
    if (t < nb) boff[t] = s[t] - v;
}

__global__ void k_scan_c(int* __restrict__ excl, const int* __restrict__ boff, int n) {
    int idx = blockIdx.x * 256 + threadIdx.x;
    if (idx < n) excl[idx] += boff[blockIdx.x];
}

// ---- partition: cbuf[pos]=(col<<16)|row by col>>8; rbuf[pos]=row (u16) by row>>8 ----
__global__ __launch_bounds__(1024) void k_part(const int* __restrict__ row,
                                               const int* __restrict__ col, int E, int chunk,
                                               const int* __restrict__ shist,
                                               unsigned* __restrict__ cbuf,
                                               unsigned short* __restrict__ rbuf) {
    __shared__ int offc[256], offr[256];
    int t = threadIdx.x, b = blockIdx.x;
    if (t < 256) {
        offc[t] = shist[t * 256 + b];
        offr[t] = shist[65536 + t * 256 + b] - E;
    }
    __syncthreads();
    int lo = b * chunk, hi = min(E, lo + chunk);
    for (int i = lo + t; i < hi; i += 1024) {
        int r = row[i], c = col[i];
        int pc = atomicAdd(&offc[c >> 8], 1);
        cbuf[pc] = ((unsigned)c << 16) | (unsigned)r;
        int pr = atomicAdd(&offr[r >> 8], 1);
        rbuf[pr] = (unsigned short)r;
    }
}

// ---- per row-bucket: exact out-degree -> dis ----
__global__ __launch_bounds__(256) void k_deg2(const unsigned short* __restrict__ rbuf,
                                              const int* __restrict__ shist, int N, int E,
                                              float* __restrict__ dis) {
    __shared__ int cnt[256];
    int t = threadIdx.x, b = blockIdx.x;
    cnt[t] = 0;
    __syncthreads();
    int rs = shist[65536 + b * 256] - E;
    int re = (b == 255) ? E : (shist[65536 + (b + 1) * 256] - E);
    for (int i = rs + t; i < re; i += 256) atomicAdd(&cnt[rbuf[i] & 255], 1);
    __syncthreads();
    int node = b * 256 + t;
    if (node < N) dis[node] = rsqrtf((float)(cnt[t] + 1));   // +1 self loop
}

// ---- per col-bucket: cntC/colStart + eSrc[pos] = row (u16) ----
__global__ __launch_bounds__(256) void k_csr(const unsigned* __restrict__ cbuf,
                                             const int* __restrict__ shist, int N, int E,
                                             int* __restrict__ cntC, int* __restrict__ colStart,
                                             unsigned short* __restrict__ eSrc) {
    __shared__ int cnt[256], ls[256], cnt2[256];
    int t = threadIdx.x, b = blockIdx.x;
    cnt[t] = 0; cnt2[t] = 0;
    __syncthreads();
    int cs = shist[b * 256];
    int ce = (b == 255) ? E : shist[(b + 1) * 256];
    for (int i = cs + t; i < ce; i += 256) atomicAdd(&cnt[(cbuf[i] >> 16) & 255], 1);
    __syncthreads();
    int v = cnt[t];
    ls[t] = v;
    __syncthreads();
    for (int off = 1; off < 256; off <<= 1) {
        int u = (t >= off) ? ls[t - off] : 0;
        __syncthreads();
        ls[t] += u;
        __syncthreads();
    }
    int excl = ls[t] - v;
    int c = b * 256 + t;
    if (c < N) { cntC[c] = v; colStart[c] = cs + excl; }
    __syncthreads();
    ls[t] = excl;
    __syncthreads();
    for (int i = cs + t; i < ce; i += 256) {
        unsigned e = cbuf[i];
        int d = (e >> 16) & 255;
        int pos = cs + ls[d] + atomicAdd(&cnt2[d], 1);
        eSrc[pos] = (unsigned short)(e & 0xFFFFu);
    }
}

// ---- xt[n][d] = bf16( dis[n] * (priv ? C1*x+C0 : x) ) ----
__global__ void k_xt(const float* __restrict__ x, const int* __restrict__ priv,
                     const float* __restrict__ dis, unsigned short* __restrict__ xt, int N) {
    int idx = blockIdx.x * blockDim.x + threadIdx.x;    // one float4 per thread
    if (idx >= N * 16) return;
    int node = idx >> 4;
    float dv = dis[node];
    int p = priv[node];
    float4 v = ((const float4*)x)[idx];
    float4 tr;
    tr.x = p ? fmaf(C1, v.x, C0) : v.x;
    tr.y = p ? fmaf(C1, v.y, C0) : v.y;
    tr.z = p ? fmaf(C1, v.z, C0) : v.z;
    tr.w = p ? fmaf(C1, v.w, C0) : v.w;
    ushort4 o;
    o.x = f2bf(dv * tr.x); o.y = f2bf(dv * tr.y);
    o.z = f2bf(dv * tr.z); o.w = f2bf(dv * tr.w);
    ((ushort4*)xt)[idx] = o;
}

// conv1 by gather: agg1[c] = dis_c * (xt_c + sum_r xt_r); wave per c, lane = dim
__global__ __launch_bounds__(256) void k_gather1(const unsigned short* __restrict__ xt,
                                                 const unsigned short* __restrict__ eSrc,
                                                 const int* __restrict__ colStart,
                                                 const int* __restrict__ cntC,
                                                 const float* __restrict__ dis,
                                                 float* __restrict__ agg1, int N) {
    int t = blockIdx.x * blockDim.x + threadIdx.x;
    int c = t >> 6, d = t & 63;
    if (c >= N) return;
    float s = bf2f(xt[(size_t)c * 64 + d]);   // self loop term
    int start = colStart[c], cnt = cntC[c];
    for (int base = 0; base < cnt; base += 64) {
        int m = min(cnt - base, 64);
        int ids = (d < m) ? (int)eSrc[start + base + d] : 0;
        int k = 0;
        for (; k + 4 <= m; k += 4) {
            int r0 = __shfl(ids, k),     r1 = __shfl(ids, k + 1);
            int r2 = __shfl(ids, k + 2), r3 = __shfl(ids, k + 3);
            float x0 = bf2f(xt[(size_t)r0 * 64 + d]);
            float x1 = bf2f(xt[(size_t)r1 * 64 + d]);
            float x2 = bf2f(xt[(size_t)r2 * 64 + d]);
            float x3 = bf2f(xt[(size_t)r3 * 64 + d]);
            s += x0; s += x1; s += x2; s += x3;
        }
        for (; k < m; ++k) {
            int r = __shfl(ids, k);
            s += bf2f(xt[(size_t)r * 64 + d]);
        }
    }
    agg1[(size_t)c * 64 + d] = dis[c] * s;
}

// fused MLP: hps = dis * (relu(agg1 @ W1 + b1) @ W2), bf16 out; one 64-node tile/block
__global__ __launch_bounds__(256) void k_mlp_fused(const float* __restrict__ agg1,
                                                   const float* __restrict__ W1,
                                                   const float* __restrict__ b1,
                                                   const float* __restrict__ W2,
                                                   const float* __restrict__ dis,
                                                   unsigned short* __restrict__ hps, int N) {
    __shared__ float hidT[128 * 68];        // 34816 B; As = rows 0..63
    __shared__ float W2s[128 * 32];         // 16 KB
    float* As = hidT;
    const int t = threadIdx.x;
    const int base = blockIdx.x * 64;

    for (int i = t * 4; i < 128 * 32; i += 1024)
        *(float4*)&W2s[i] = *(const float4*)&W2[i];

    {
        int kq = t & 15, mm = t >> 4;
        #pragma unroll
        for (int p = 0; p < 4; ++p) {
            int m = mm + p * 16;
            int node = base + m;
            if (node >= N) node = N - 1;
            const float4 v = *(const float4*)&agg1[(size_t)node * 64 + kq * 4];
            As[(kq * 4 + 0) * 68 + m] = v.x;
            As[(kq * 4 + 1) * 68 + m] = v.y;
            As[(kq * 4 + 2) * 68 + m] = v.z;
            As[(kq * 4 + 3) * 68 + m] = v.w;
        }
    }
    __syncthreads();

    const int tn = t & 31;
    const int tm = t >> 5;
    float4 bv = *(const float4*)&b1[tn * 4];
    float acc[8][4];
    #pragma unroll
    for (int i = 0; i < 8; ++i) {
        acc[i][0] = bv.x; acc[i][1] = bv.y; acc[i][2] = bv.z; acc[i][3] = bv.w;
    }
    #pragma unroll 4
    for (int k = 0; k < 64; ++k) {
        float4 w  = *(const float4*)&W1[k * 128 + tn * 4];
        float4 a0 = *(const float4*)&As[k * 68 + tm * 8];
        float4 a1 = *(const float4*)&As[k * 68 + tm * 8 + 4];
        const float av[8] = {a0.x, a0.y, a0.z, a0.w, a1.x, a1.y, a1.z, a1.w};
        #pragma unroll
        for (int i = 0; i < 8; ++i) {
            acc[i][0] = fmaf(av[i], w.x, acc[i][0]);
            acc[i][1] = fmaf(av[i], w.y, acc[i][1]);
            acc[i][2] = fmaf(av[i], w.z, acc[i][2]);
            acc[i][3] = fmaf(av[i], w.w, acc[i][3]);
        }
    }
    __syncthreads();

    #pragma unroll
    for (int j = 0; j < 4; ++j)
        #pragma unroll
        for (int i = 0; i < 8; ++i)
            hidT[(tn * 4 + j) * 68 + tm * 8 + i] = fmaxf(acc[i][j], 0.f);
    __syncthreads();

    const int to  = t & 15;
    const int tm2 = t >> 4;
    float o0[4] = {0.f, 0.f, 0.f, 0.f};
    float o1[4] = {0.f, 0.f, 0.f, 0.f};
    #pragma unroll 4
    for (int kh = 0; kh < 128; ++kh) {
        float4 a = *(const float4*)&hidT[kh * 68 + tm2 * 4];
        float2 w = *(const float2*)&W2s[kh * 32 + to * 2];
        const float av[4] = {a.x, a.y, a.z, a.w};
        #pragma unroll
        for (int i = 0; i < 4; ++i) {
            o0[i] = fmaf(av[i], w.x, o0[i]);
            o1[i] = fmaf(av[i], w.y, o1[i]);
        }
    }
    #pragma unroll
    for (int i = 0; i < 4; ++i) {
        int node = base + tm2 * 4 + i;
        if (node < N) {
            float dv = dis[node];
            ushort2 o = make_ushort2(f2bf(o0[i] * dv), f2bf(o1[i] * dv));
            *(ushort2*)&hps[(size_t)node * 32 + to * 2] = o;
        }
    }
}

// conv2 by gather: out[c] = b2 - dis_c * (hps_c + sum_r hps_r); 32 lanes per c
__global__ __launch_bounds__(256) void k_gather2(const unsigned short* __restrict__ hps,
                                                 const unsigned short* __restrict__ eSrc,
                                                 const int* __restrict__ colStart,
                                                 const int* __restrict__ cntC,
                                                 const float* __restrict__ dis,
                                                 const float* __restrict__ b2,
                                                 float* __restrict__ out, int N) {
    int t = blockIdx.x * blockDim.x + threadIdx.x;
    int c = t >> 5, j = t & 31;
    if (c >= N) return;
    float s = bf2f(hps[(size_t)c * 32 + j]);   // self loop
    int start = colStart[c], cnt = cntC[c];
    for (int base = 0; base < cnt; base += 32) {
        int m = min(cnt - base, 32);
        int ids = (j < m) ? (int)eSrc[start + base + j] : 0;
        int k = 0;
        for (; k + 4 <= m; k += 4) {
            int r0 = __shfl(ids, k, 32),     r1 = __shfl(ids, k + 1, 32);
            int r2 = __shfl(ids, k + 2, 32), r3 = __shfl(ids, k + 3, 32);
            float h0 = bf2f(hps[(size_t)r0 * 32 + j]);
            float h1 = bf2f(hps[(size_t)r1 * 32 + j]);
            float h2 = bf2f(hps[(size_t)r2 * 32 + j]);
            float h3 = bf2f(hps[(size_t)r3 * 32 + j]);
            s += h0; s += h1; s += h2; s += h3;
        }
        for (; k < m; ++k) {
            int r = __shfl(ids, k, 32);
            s += bf2f(hps[(size_t)r * 32 + j]);
        }
    }
    out[(size_t)c * 32 + j] = b2[j] - dis[c] * s;
}

extern "C" void kernel_launch(void* const* d_in, const int* in_sizes, int n_in,
                              void* d_out, int out_size, void* d_ws, size_t ws_size,
                              hipStream_t stream) {
    const float* x    = (const float*)d_in[0];
    const int*   ei   = (const int*)d_in[1];
    const int*   priv = (const int*)d_in[2];
    const float* W1   = (const float*)d_in[3];
    const float* b1   = (const float*)d_in[4];
    const float* W2   = (const float*)d_in[5];
    const float* b2   = (const float*)d_in[6];
    float* out = (float*)d_out;

    const int N = in_sizes[2];
    const int E = in_sizes[1] / 2;
    const int* row = ei;
    const int* col = ei + E;

    char* ws = (char*)d_ws;
    size_t off = 0;
    auto take = [&](size_t bytes) { char* p = ws + off; off = (off + bytes + 255) & ~(size_t)255; return p; };
    int*            hist     = (int*)           take((size_t)131072 * 4);
    int*            shist    = (int*)           take((size_t)131072 * 4);
    int*            bsum     = (int*)           take(512 * 4);
    int*            boff     = (int*)           take(512 * 4);
    unsigned*       cbuf     = (unsigned*)      take((size_t)E * 4);
    unsigned short* rbuf     = (unsigned short*)take((size_t)E * 2);
    float*          dis      = (float*)         take((size_t)N * 4);
    int*            cntC     = (int*)           take((size_t)N * 4);
    int*            colStart = (int*)           take((size_t)N * 4);
    unsigned short* eSrc     = (unsigned short*)take((size_t)E * 2);
    unsigned short* xt       = (unsigned short*)take((size_t)N * 64 * 2);
    float*          agg1     = (float*)         take((size_t)N * 64 * 4);
    unsigned short* hps      = (unsigned short*)take((size_t)N * 32 * 2);
    (void)ws_size;

    const int chunk = (E + 255) / 256;
    const int nbk = (N + 255) / 256;     // node buckets (196)

    k_hist2    <<<256, 1024, 0, stream>>>(row, col, E, chunk, hist);
    k_scan_a   <<<512, 256, 0, stream>>>(hist, shist, bsum, 131072);
    k_scan_b512<<<1, 512, 0, stream>>>(bsum, boff, 512);
    k_scan_c   <<<512, 256, 0, stream>>>(shist, boff, 131072);
    k_part     <<<256, 1024, 0, stream>>>(row, col, E, chunk, shist, cbuf, rbuf);
    k_deg2     <<<nbk, 256, 0, stream>>>(rbuf, shist, N, E, dis);
    k_csr      <<<nbk, 256, 0, stream>>>(cbuf, shist, N, E, cntC, colStart, eSrc);
    k_xt       <<<(N * 16 + 255) / 256, 256, 0, stream>>>(x, priv, dis, xt, N);
    k_gather1  <<<((size_t)N * 64 + 255) / 256, 256, 0, stream>>>(xt, eSrc, colStart, cntC, dis, agg1, N);
    k_mlp_fused<<<(N + 63) / 64, 256, 0, stream>>>(agg1, W1, b1, W2, dis, hps, N);
    k_gather2  <<<((size_t)N * 32 + 255) / 256, 256, 0, stream>>>(hps, eSrc, colStart, cntC, dis, b2, out, N);
}